// Round 2
// baseline (408.546 us; speedup 1.0000x reference)
//
#include <hip/hip_runtime.h>

typedef _Float16 half_t;
typedef __attribute__((ext_vector_type(8))) _Float16 half8;
typedef __attribute__((ext_vector_type(4))) float f32x4;

#define NB 32
#define NH 128
#define NW 128
#define NOH 122
#define NOW 122
#define NOC 512
#define NTAP 49
#define KPAD 64
#define NCH 4     // oh chunks per (b,fg)
#define RPC 31    // rows per chunk (4*31 = 124 >= 122)

// ws layout (bytes):
//   gh: [32][128][128] half  @ 0         (1048576)
//   Wh: [512][64]      half  @ 1048576   (65536)
//   w2: [512]          float @ 1114112   (2048)
//   x2: [32][122][122] float @ 1116160   (1905152)

__global__ __launch_bounds__(256) void k_gray(const float* __restrict__ x,
                                              half_t* __restrict__ gh) {
    int t = blockIdx.x * 256 + threadIdx.x;
    if (t >= NB * NH * NW) return;
    int b = t >> 14;
    int pix = t & 16383;
    const float* xb = x + (size_t)b * 3 * 16384;
    float g = 0.2989f * xb[pix] + 0.587f * xb[16384 + pix] + 0.114f * xb[32768 + pix];
    gh[t] = (half_t)g;
}

__global__ __launch_bounds__(64) void k_w(const float* __restrict__ w,
                                          half_t* __restrict__ Wh,
                                          float* __restrict__ w2) {
    int o = blockIdx.x * 64 + threadIdx.x;
    if (o >= NOC) return;
    float s = 0.f;
    for (int t = 0; t < KPAD; ++t) {
        float v = (t < NTAP) ? w[o * NTAP + t] : 0.f;
        half_t h = (half_t)v;
        Wh[o * KPAD + t] = h;
        float f = (float)h;
        s += f * f;
    }
    w2[o] = s;
}

__global__ __launch_bounds__(256) void k_x2(const half_t* __restrict__ gh,
                                            float* __restrict__ x2) {
    int t = blockIdx.x * 256 + threadIdx.x;
    if (t >= NB * NOH * NOW) return;
    int b = t / (NOH * NOW);
    int rem = t - b * (NOH * NOW);
    int oh = rem / NOW;
    int ow = rem - oh * NOW;
    const half_t* g = gh + ((size_t)b * NH + oh) * NW + ow;
    float s = 0.f;
#pragma unroll
    for (int kh = 0; kh < 7; ++kh) {
#pragma unroll
        for (int kw = 0; kw < 7; ++kw) {
            float v = (float)g[kh * NW + kw];
            s += v * v;
        }
    }
    x2[t] = s;
}

// Persistent-row main kernel: each block owns (b, fg, oh-chunk), keeps A/w2 in
// registers, and rolls a circular 8-slot LDS row buffer over consecutive oh.
__global__ __launch_bounds__(256) void k_main(const half_t* __restrict__ gh,
                                              const half_t* __restrict__ Wh,
                                              const float* __restrict__ w2,
                                              const float* __restrict__ x2,
                                              const float* __restrict__ stdp,
                                              float* __restrict__ out) {
    const int fg = blockIdx.x;               // 0..7  (64 filters)
    const int ch = blockIdx.y;               // 0..3  (oh chunk)
    const int b  = blockIdx.z;               // 0..31
    const int oh0 = ch * RPC;
    const int nrows = (NOH - oh0 < RPC) ? (NOH - oh0) : RPC;

    __shared__ half_t gS[8][136];            // circular row buffer, slot = row & 7

    const int tid  = threadIdx.x;
    const int wave = tid >> 6;
    const int lane = tid & 63;
    const int col  = lane & 15;
    const int kq   = lane >> 4;
    const int n0   = wave * 32;

    // A fragments (reused for all rows): A[row=filter (lane&15)][k=kq*8+i]
    half8 afrag[4][2];
#pragma unroll
    for (int mi = 0; mi < 4; ++mi)
#pragma unroll
        for (int ks = 0; ks < 2; ++ks) {
            const half_t* ap = Wh + ((size_t)(fg * 64 + mi * 16 + col) * KPAD + ks * 32 + kq * 8);
            afrag[mi][ks] = *(const half8*)ap;
        }

    // w2 for this lane's 16 output filters: o = fg*64 + mi*16 + kq*4 + r
    f32x4 w2c[4];
#pragma unroll
    for (int mi = 0; mi < 4; ++mi)
        w2c[mi] = *(const f32x4*)(w2 + fg * 64 + mi * 16 + kq * 4);

    // Prologue: stage rows oh0..oh0+5; zero-fill the 8th slot ((oh0+7)&7) so
    // the first iteration's pad-tap reads (kh=7..9, weight==0) see finite data.
    for (int idx = tid; idx < 7 * 136; idx += 256) {
        int r = idx / 136;
        int c = idx - r * 136;
        if (r < 6) {
            half_t hv = (c < 128) ? gh[((size_t)b * NH + (oh0 + r)) * NW + c] : (half_t)0.f;
            gS[(oh0 + r) & 7][c] = hv;
        } else {
            gS[(oh0 + 7) & 7][c] = (half_t)0.f;
        }
    }

    const float sv = stdp[0];
    const float inv2s2 = 0.5f / (sv * sv);

    for (int oh = oh0; oh < oh0 + nrows; ++oh) {
        // Stage row oh+6 into slot (oh+6)&7 (disjoint from rows oh-read set of
        // the previous iteration; one barrier per iteration suffices).
        if (tid < 136) {
            int row = oh + 6;                 // <= 127, always in-bounds
            half_t hv = (tid < 128) ? gh[((size_t)b * NH + row) * NW + tid] : (half_t)0.f;
            gS[row & 7][tid] = hv;
        }
        __syncthreads();

        // B fragments: B[k][col=position]; tap t -> (kh,kw); pad taps (t>=49)
        // read stale rows but their A-weights are zero.
        half8 bfrag[2][2];
#pragma unroll
        for (int ni = 0; ni < 2; ++ni)
#pragma unroll
            for (int ks = 0; ks < 2; ++ks) {
                half8 v;
#pragma unroll
                for (int i = 0; i < 8; ++i) {
                    int t = ks * 32 + kq * 8 + i;
                    int kh = (t * 37) >> 8;   // t/7 for t<64
                    int kw = t - kh * 7;
                    v[i] = gS[(oh + kh) & 7][n0 + ni * 16 + col + kw];
                }
                bfrag[ni][ks] = v;
            }

        f32x4 acc[4][2];
#pragma unroll
        for (int mi = 0; mi < 4; ++mi)
#pragma unroll
            for (int ni = 0; ni < 2; ++ni) {
                f32x4 z = {0.f, 0.f, 0.f, 0.f};
                acc[mi][ni] = z;
            }

#pragma unroll
        for (int ks = 0; ks < 2; ++ks)
#pragma unroll
            for (int mi = 0; mi < 4; ++mi)
#pragma unroll
                for (int ni = 0; ni < 2; ++ni)
                    acc[mi][ni] = __builtin_amdgcn_mfma_f32_16x16x32_f16(
                        afrag[mi][ks], bfrag[ni][ks], acc[mi][ni], 0, 0, 0);

        // Epilogue: sq = x2 + w2 - 2*xw, clamp, exp, store.
#pragma unroll
        for (int ni = 0; ni < 2; ++ni) {
            const int p = n0 + ni * 16 + col;
            const bool pok = p < NOW;
            const float x2v = pok ? x2[((size_t)b * NOH + oh) * NOW + p] : 0.f;
#pragma unroll
            for (int mi = 0; mi < 4; ++mi) {
#pragma unroll
                for (int r = 0; r < 4; ++r) {
                    const int o = fg * 64 + mi * 16 + kq * 4 + r;
                    float sq = fmaxf(fmaf(-2.f, acc[mi][ni][r], x2v + w2c[mi][r]), 0.f);
                    float res = __expf(-sq * inv2s2);
                    if (pok) out[(((size_t)b * NOC + o) * NOH + oh) * NOW + p] = res;
                }
            }
        }
        // No trailing barrier needed: next iteration writes slot (oh+7)&7,
        // which is not read by this iteration's gather.
    }
}

extern "C" void kernel_launch(void* const* d_in, const int* in_sizes, int n_in,
                              void* d_out, int out_size, void* d_ws, size_t ws_size,
                              hipStream_t stream) {
    const float* x    = (const float*)d_in[0];
    const float* w    = (const float*)d_in[1];
    const float* stdp = (const float*)d_in[2];
    float* out = (float*)d_out;

    char* ws = (char*)d_ws;
    half_t* gh = (half_t*)ws;
    half_t* Wh = (half_t*)(ws + 1048576);
    float*  w2 = (float*)(ws + 1114112);
    float*  x2 = (float*)(ws + 1116160);

    k_gray<<<(NB * NH * NW + 255) / 256, 256, 0, stream>>>(x, gh);
    k_w<<<(NOC + 63) / 64, 64, 0, stream>>>(w, Wh, w2);
    k_x2<<<(NB * NOH * NOW + 255) / 256, 256, 0, stream>>>(gh, x2);

    dim3 grid(8, NCH, NB);
    k_main<<<grid, 256, 0, stream>>>(gh, Wh, w2, x2, stdp, out);
}

// Round 3
// 407.815 us; speedup vs baseline: 1.0018x; 1.0018x over previous
//
#include <hip/hip_runtime.h>

typedef _Float16 half_t;
typedef __attribute__((ext_vector_type(4))) _Float16 half4;
typedef __attribute__((ext_vector_type(8))) _Float16 half8;
typedef __attribute__((ext_vector_type(4))) float f32x4;

#define NB 32
#define NH 128
#define NW 128
#define NOH 122
#define NOW 122
#define NOC 512
#define KPAD 64

// ws layout (bytes):
//   gh: [32][128][128] half  @ 0         (1048576)
//   Wh: [512][64]      half  @ 1048576   (65536)   t = kh*8+kw, zero-padded
//   w2: [512]          float @ 1114112   (2048)
//   x2: [32][122][122] float @ 1116160   (1905152 + 64 slack)
//   Sg: [32][128][122] float @ 3021440   (1998848)  row-sums of g^2

__global__ __launch_bounds__(256) void k_gray(const float* __restrict__ x,
                                              half_t* __restrict__ gh) {
    int t = blockIdx.x * 256 + threadIdx.x;   // one thread = 4 pixels
    if (t >= NB * NH * NW / 4) return;
    int b = t >> 12;
    int pix4 = t & 4095;
    const float* xb = x + (size_t)b * 3 * 16384 + pix4 * 4;
    f32x4 r = *(const f32x4*)xb;
    f32x4 g = *(const f32x4*)(xb + 16384);
    f32x4 bl = *(const f32x4*)(xb + 32768);
    half4 o;
#pragma unroll
    for (int i = 0; i < 4; ++i)
        o[i] = (half_t)(0.2989f * r[i] + 0.587f * g[i] + 0.114f * bl[i]);
    *(half4*)(gh + (size_t)t * 4) = o;
}

__global__ __launch_bounds__(64) void k_w(const float* __restrict__ w,
                                          half_t* __restrict__ Wh,
                                          float* __restrict__ w2) {
    int o = blockIdx.x * 64 + threadIdx.x;
    if (o >= NOC) return;
    float s = 0.f;
    for (int t = 0; t < KPAD; ++t) {
        int kh = t >> 3, kw = t & 7;
        float v = (kh < 7 && kw < 7) ? w[o * 49 + kh * 7 + kw] : 0.f;
        half_t h = (half_t)v;
        Wh[o * KPAD + t] = h;
        float f = (float)h;
        s += f * f;
    }
    w2[o] = s;
}

// Sg[b][h][p] = sum_{kw<7} gh[b][h][p+kw]^2   (separable pass 1)
__global__ __launch_bounds__(256) void k_rs(const half_t* __restrict__ gh,
                                            float* __restrict__ Sg) {
    int t = blockIdx.x * 256 + threadIdx.x;
    if (t >= NB * NH * NOW) return;
    int b = t / (NH * NOW);
    int rem = t - b * (NH * NOW);
    int h = rem / NOW;
    int p = rem - h * NOW;
    const half_t* g = gh + ((size_t)b * NH + h) * NW + p;
    float s = 0.f;
#pragma unroll
    for (int kw = 0; kw < 7; ++kw) {
        float v = (float)g[kw];
        s += v * v;
    }
    Sg[t] = s;
}

// x2[b][oh][p] = sum_{kh<7} Sg[b][oh+kh][p]   (separable pass 2)
__global__ __launch_bounds__(256) void k_x2(const float* __restrict__ Sg,
                                            float* __restrict__ x2) {
    int t = blockIdx.x * 256 + threadIdx.x;
    if (t >= NB * NOH * NOW) return;
    int b = t / (NOH * NOW);
    int rem = t - b * (NOH * NOW);
    int oh = rem / NOW;
    int p = rem - oh * NOW;
    const float* s0 = Sg + ((size_t)b * NH + oh) * NOW + p;
    float s = 0.f;
#pragma unroll
    for (int kh = 0; kh < 7; ++kh) s += s0[kh * NOW];
    x2[t] = s;
}

// Main: M = 128 positions (4 waves x 32), N = 64 filters, K = 64 padded taps.
// A (window): lane row = position p = n0 + mi*16 + (lane&15); elem i -> tap
//   t = ks*32 + kq*8 + i = (kh = ks*4+kq)*8 + (kw = i) -> gS[kh][p+i].
// B (weights): lane col = filter o = fg*64 + ni*16 + (lane&15); elem i ->
//   Wh[o][(ks*4+kq)*8 + i] (contiguous, 16B aligned).
// D: col = lane&15 -> filter-tile idx; row = kq*4 + r -> p offset -> f32x4
//   covers 4 consecutive p -> global_store_dwordx4.
__global__ __launch_bounds__(256) void k_main(const half_t* __restrict__ gh,
                                              const half_t* __restrict__ Wh,
                                              const float* __restrict__ w2,
                                              const float* __restrict__ x2,
                                              const float* __restrict__ stdp,
                                              float* __restrict__ out) {
    const int fg = blockIdx.x;   // 0..7
    const int oh = blockIdx.y;   // 0..121
    const int b  = blockIdx.z;   // 0..31

    __shared__ half_t gS[8][136];  // rows 0..6 real (oh+r), row 7 + cols>=128 zero

    const int tid = threadIdx.x;
    for (int idx = tid; idx < 8 * 136; idx += 256) {
        int r = idx / 136;
        int c = idx - r * 136;
        half_t hv = (half_t)0.f;
        if (r < 7 && c < 128) hv = gh[((size_t)b * NH + (oh + r)) * NW + c];
        gS[r][c] = hv;
    }

    const int wave = tid >> 6;
    const int lane = tid & 63;
    const int col  = lane & 15;
    const int kq   = lane >> 4;
    const int n0   = wave * 32;

    // Weight (B) fragments: contiguous half8, reused across mi.
    half8 wfrag[4][2];
#pragma unroll
    for (int ni = 0; ni < 4; ++ni)
#pragma unroll
        for (int ks = 0; ks < 2; ++ks)
            wfrag[ni][ks] = *(const half8*)(Wh + ((size_t)(fg * 64 + ni * 16 + col) * KPAD
                                                  + (ks * 4 + kq) * 8));

    __syncthreads();

    // Window (A) fragments.
    half8 afrag[2][2];
#pragma unroll
    for (int mi = 0; mi < 2; ++mi) {
        const int p = n0 + mi * 16 + col;
#pragma unroll
        for (int ks = 0; ks < 2; ++ks) {
            const half_t* src = &gS[ks * 4 + kq][p];
            half8 v;
#pragma unroll
            for (int i = 0; i < 8; ++i) v[i] = src[i];
            afrag[mi][ks] = v;
        }
    }

    f32x4 acc[2][4];
#pragma unroll
    for (int mi = 0; mi < 2; ++mi)
#pragma unroll
        for (int ni = 0; ni < 4; ++ni) {
            f32x4 z = {0.f, 0.f, 0.f, 0.f};
            acc[mi][ni] = z;
        }

#pragma unroll
    for (int ks = 0; ks < 2; ++ks)
#pragma unroll
        for (int mi = 0; mi < 2; ++mi)
#pragma unroll
            for (int ni = 0; ni < 4; ++ni)
                acc[mi][ni] = __builtin_amdgcn_mfma_f32_16x16x32_f16(
                    afrag[mi][ks], wfrag[ni][ks], acc[mi][ni], 0, 0, 0);

    const float sv = stdp[0];
    const float inv2s2 = 0.5f / (sv * sv);
    const size_t rowBase = ((size_t)b * NOH + oh) * NOW;

#pragma unroll
    for (int mi = 0; mi < 2; ++mi) {
        const int p0 = n0 + mi * 16 + kq * 4;   // this lane's 4 consecutive p
        if (p0 >= NOW) continue;
        const f32x4 x2v = *(const f32x4*)(x2 + rowBase + p0);  // +64B ws slack
#pragma unroll
        for (int ni = 0; ni < 4; ++ni) {
            const int o = fg * 64 + ni * 16 + col;
            const float w2v = w2[o];
            f32x4 res;
#pragma unroll
            for (int r = 0; r < 4; ++r) {
                float sq = fmaxf(fmaf(-2.f, acc[mi][ni][r], x2v[r] + w2v), 0.f);
                res[r] = __expf(-sq * inv2s2);
            }
            float* dst = out + (((size_t)b * NOC + o) * NOH + oh) * NOW + p0;
            if (p0 + 3 < NOW) {
                *(f32x4*)dst = res;
            } else {
#pragma unroll
                for (int r = 0; r < 4; ++r)
                    if (p0 + r < NOW) dst[r] = res[r];
            }
        }
    }
}

extern "C" void kernel_launch(void* const* d_in, const int* in_sizes, int n_in,
                              void* d_out, int out_size, void* d_ws, size_t ws_size,
                              hipStream_t stream) {
    const float* x    = (const float*)d_in[0];
    const float* w    = (const float*)d_in[1];
    const float* stdp = (const float*)d_in[2];
    float* out = (float*)d_out;

    char* ws = (char*)d_ws;
    half_t* gh = (half_t*)ws;
    half_t* Wh = (half_t*)(ws + 1048576);
    float*  w2 = (float*)(ws + 1114112);
    float*  x2 = (float*)(ws + 1116160);
    float*  Sg = (float*)(ws + 3021440);

    k_gray<<<(NB * NH * NW / 4 + 255) / 256, 256, 0, stream>>>(x, gh);
    k_w<<<(NOC + 63) / 64, 64, 0, stream>>>(w, Wh, w2);
    k_rs<<<(NB * NH * NOW + 255) / 256, 256, 0, stream>>>(gh, Sg);
    k_x2<<<(NB * NOH * NOW + 255) / 256, 256, 0, stream>>>(Sg, x2);

    dim3 grid(8, NOH, NB);
    k_main<<<grid, 256, 0, stream>>>(gh, Wh, w2, x2, stdp, out);
}